// Round 1
// baseline (252.505 us; speedup 1.0000x reference)
//
#include <hip/hip_runtime.h>

// MGN_NET: 3x NNConv(mean) + ReLU, then pairwise-L1 CBT [35x35]. All fp32.
// 2 dispatches: init (zero barrier counter) + mega-kernel (238 blocks x 512)
// with 5 software grid barriers between phases:
//   P1  (35 blk): per-node edge lists + x1            -> x1m, elist, cnt
//   P2a (238 blk): layer-2 edge messages, i-halves    -> mp[2][E][256]
//   P2b (35 blk): gather + lin2 matvec                -> x2m
//   P3a (238 blk): layer-3 edge messages              -> mp3[E][64]
//   P3b (35 blk): gather + lin3 matvec                -> x3m
//   P4  (35 blk): pairwise-L1 CBT                     -> out
// 238 blocks <= 256 CUs => whole grid always co-resident => barrier is safe.
// No atomics, no buffer zeroing: every ws word is written before it is read.

#define NN 35
#define NE 1190
#define NBLK 238
#define TE2 10   // edges per group, layer 2 (119 groups x 2 i-halves = 238)
#define TE3 5    // edges per group, layer 3 (238 groups)

// float offsets into ws
#define OFF_X1    64        // 35*256
#define OFF_CNT   9024      // 35
#define OFF_ELIST 9088      // ints, 35*1190 (ends 50738)
#define OFF_MP    51200     // 2*1190*256 (ends 660480)
#define OFF_MP3   660480    // 1190*64  (ends 736640)
#define OFF_X2    736640    // 35*256   (ends 745600)
#define OFF_X3    745600    // 35*64    (ends 747840)

__global__ __launch_bounds__(64) void init_k(unsigned* bar) {
    if (threadIdx.x < 16) bar[threadIdx.x] = 0u;
}

// Software grid barrier: monotonic counter, device-scope.
// Release fence before arrive; acquire fence after the spin. Only thread 0
// spins; the rest park at s_barrier. Counter target = NBLK * phase.
__device__ __forceinline__ void gbar(unsigned* bar, unsigned target) {
    __syncthreads();
    if (threadIdx.x == 0) {
        __threadfence();
        atomicAdd(bar, 1u);
        while (__hip_atomic_load(bar, __ATOMIC_RELAXED,
                                 __HIP_MEMORY_SCOPE_AGENT) < target)
            __builtin_amdgcn_s_sleep(2);
        __threadfence();
    }
    __syncthreads();
}

__global__ __launch_bounds__(512, 2) void mega_k(
    float* __restrict__ ws, const float* __restrict__ x,
    const float* __restrict__ ea, const int* __restrict__ ei,
    const float* __restrict__ w1, const float* __restrict__ b1w,
    const float* __restrict__ lin1, const float* __restrict__ b1,
    const float* __restrict__ w2, const float* __restrict__ b2w,
    const float* __restrict__ lin2, const float* __restrict__ b2,
    const float* __restrict__ w3, const float* __restrict__ b3w,
    const float* __restrict__ lin3, const float* __restrict__ b3,
    float* __restrict__ out) {
    __shared__ float smem[4096];   // 16 KiB, reused across phases
    unsigned* bar = (unsigned*)ws;
    const int tid = threadIdx.x;
    const int bid = blockIdx.x;
    int* elist_all = (int*)(ws + OFF_ELIST);

    // ---------------- P1: edge lists + layer-1 node outputs ----------------
    if (bid < NN) {
        const int n = bid;
        int* elist = elist_all + n * NE;
        int* degS = (int*)smem;
        if (tid < 64) {  // wave 0 builds the ordered edge list via ballot
            int deg = 0;
            for (int base = 0; base < NE; base += 64) {
                const int e = base + tid;
                const bool m = (e < NE) && (ei[NE + e] == n);
                const unsigned long long mk = __ballot(m);
                if (m) elist[deg + __popcll(mk & ((1ull << tid) - 1ull))] = e;
                deg += __popcll(mk);
            }
            if (tid == 0) { degS[0] = deg; ws[OFF_CNT + n] = (float)deg; }
        }
        __syncthreads();
        const int deg = degS[0];
        const int o = tid & 255, ech = tid >> 8;
        const float* wr = w1 + o * 6;
        const float wv0 = wr[0], wv1 = wr[1], wv2 = wr[2];
        const float wv3 = wr[3], wv4 = wr[4], wv5 = wr[5];
        const float bb = b1w[o];
        float a = 0.f;
        for (int k = ech; k < deg; k += 2) {
            const int e = elist[k];
            const float* eap = ea + e * 6;
            float d = bb;
            d = fmaf(eap[0], wv0, d); d = fmaf(eap[1], wv1, d);
            d = fmaf(eap[2], wv2, d); d = fmaf(eap[3], wv3, d);
            d = fmaf(eap[4], wv4, d); d = fmaf(eap[5], wv5, d);
            a = fmaf(x[ei[e]], fmaxf(d, 0.f), a);
        }
        float* part = smem + 1024;
        if (ech == 1) part[o] = a;
        __syncthreads();
        if (ech == 0) {
            const float c = fmaxf((float)deg, 1.f);
            const float v = (a + part[o]) / c + x[n] * lin1[o] + b1[o];
            ws[OFF_X1 + n * 256 + o] = fmaxf(v, 0.f);
        }
    }
    gbar(bar, NBLK * 1u);

    // ---------------- P2a: layer-2 edge messages (partial over i-halves) ---
    {
        const int eg = bid >> 1, ig = bid & 1;
        const int e0 = eg * TE2;
        int* srcsS = (int*)smem;            // 10
        float* easS = smem + 16;            // 60
        float* xsS = smem + 128;            // 10*128
        float* partS = smem + 1536;         // 10*256
        if (tid < TE2) srcsS[tid] = ei[e0 + tid];
        if (tid >= 64 && tid < 64 + TE2 * 6) {
            const int t = tid - 64;
            easS[t] = ea[e0 * 6 + t];
        }
        __syncthreads();
        for (int idx = tid; idx < TE2 * 128; idx += 512) {
            const int te = idx >> 7, il = idx & 127;
            xsS[te * 128 + il] = ws[OFF_X1 + srcsS[te] * 256 + ig * 128 + il];
        }
        __syncthreads();
        const int o = tid & 255, ich = tid >> 8;
        float ear[TE2][6];
#pragma unroll
        for (int te = 0; te < TE2; te++)
#pragma unroll
            for (int v = 0; v < 6; v++) ear[te][v] = easS[te * 6 + v];
        float acc[TE2] = {};
        for (int ii = 0; ii < 64; ii++) {
            const int il = ich * 64 + ii;
            const int i = ig * 128 + il;
            const float* wp = w2 + (size_t)(i * 256 + o) * 6;
            const float2 wa = *(const float2*)wp;
            const float2 wb = *(const float2*)(wp + 2);
            const float2 wc = *(const float2*)(wp + 4);
            const float b = b2w[i * 256 + o];
#pragma unroll
            for (int te = 0; te < TE2; te += 2) {
                float dx = b, dy = b;
                dx = fmaf(ear[te][0], wa.x, dx); dy = fmaf(ear[te+1][0], wa.x, dy);
                dx = fmaf(ear[te][1], wa.y, dx); dy = fmaf(ear[te+1][1], wa.y, dy);
                dx = fmaf(ear[te][2], wb.x, dx); dy = fmaf(ear[te+1][2], wb.x, dy);
                dx = fmaf(ear[te][3], wb.y, dx); dy = fmaf(ear[te+1][3], wb.y, dy);
                dx = fmaf(ear[te][4], wc.x, dx); dy = fmaf(ear[te+1][4], wc.x, dy);
                dx = fmaf(ear[te][5], wc.y, dx); dy = fmaf(ear[te+1][5], wc.y, dy);
                dx = fmaxf(dx, 0.f);             dy = fmaxf(dy, 0.f);
                acc[te]   = fmaf(xsS[te * 128 + il], dx, acc[te]);
                acc[te+1] = fmaf(xsS[(te+1) * 128 + il], dy, acc[te+1]);
            }
        }
        if (ich == 1) {
#pragma unroll
            for (int te = 0; te < TE2; te++) partS[te * 256 + o] = acc[te];
        }
        __syncthreads();
        if (ich == 0) {
#pragma unroll
            for (int te = 0; te < TE2; te++)
                ws[OFF_MP + (size_t)(ig * NE + e0 + te) * 256 + o] =
                    acc[te] + partS[te * 256 + o];
        }
    }
    gbar(bar, NBLK * 2u);

    // ---------------- P2b: gather + lin2 matvec -> x2 ----------------------
    if (bid < NN) {
        const int n = bid;
        const int deg = (int)ws[OFF_CNT + n];
        const int* el = elist_all + n * NE;
        float* xrowS = smem;        // 256
        float* pA = smem + 256;     // 256
        float* pB = smem + 512;     // 256
        if (tid < 256) xrowS[tid] = ws[OFF_X1 + n * 256 + tid];
        __syncthreads();
        const int o = tid & 255, ich = tid >> 8;
        const float4* l4 = (const float4*)(lin2 + (size_t)o * 256 + ich * 128);
        float slin = 0.f;
#pragma unroll
        for (int k = 0; k < 32; k++) {
            const float4 wv = l4[k];
            const int i = ich * 128 + k * 4;
            slin = fmaf(wv.x, xrowS[i], slin);
            slin = fmaf(wv.y, xrowS[i+1], slin);
            slin = fmaf(wv.z, xrowS[i+2], slin);
            slin = fmaf(wv.w, xrowS[i+3], slin);
        }
        float sagg = 0.f;
        const float* mpb = ws + OFF_MP + (size_t)ich * NE * 256;
        for (int k = 0; k < deg; k++)
            sagg += mpb[(size_t)el[k] * 256 + o];
        if (ich == 1) { pA[o] = slin; pB[o] = sagg; }
        __syncthreads();
        if (ich == 0) {
            const float c = fmaxf((float)deg, 1.f);
            const float v = (sagg + pB[o]) / c + slin + pA[o] + b2[o];
            ws[OFF_X2 + n * 256 + o] = fmaxf(v, 0.f);
        }
    }
    gbar(bar, NBLK * 3u);

    // ---------------- P3a: layer-3 edge messages ---------------------------
    {
        const int e0 = bid * TE3;
        int* srcsS = (int*)smem;            // 5
        float* easS = smem + 8;             // 30
        float* xsS = smem + 256;            // 5*256
        float* partS = smem + 1536;         // 7*5*64
        if (tid < TE3) srcsS[tid] = ei[e0 + tid];
        if (tid >= 64 && tid < 64 + TE3 * 6) {
            const int t = tid - 64;
            easS[t] = ea[e0 * 6 + t];
        }
        __syncthreads();
        for (int idx = tid; idx < TE3 * 256; idx += 512) {
            const int te = idx >> 8, il = idx & 255;
            xsS[te * 256 + il] = ws[OFF_X2 + srcsS[te] * 256 + il];
        }
        __syncthreads();
        const int o3 = tid & 63, ic = tid >> 6;
        float ear[TE3][6];
#pragma unroll
        for (int te = 0; te < TE3; te++)
#pragma unroll
            for (int v = 0; v < 6; v++) ear[te][v] = easS[te * 6 + v];
        float acc[TE3] = {};
        for (int ii = 0; ii < 32; ii++) {
            const int i = ic * 32 + ii;
            const float* wp = w3 + (size_t)(i * 64 + o3) * 6;
            const float2 wa = *(const float2*)wp;
            const float2 wb = *(const float2*)(wp + 2);
            const float2 wc = *(const float2*)(wp + 4);
            const float b = b3w[i * 64 + o3];
#pragma unroll
            for (int te = 0; te < TE3; te++) {
                float d = b;
                d = fmaf(ear[te][0], wa.x, d);
                d = fmaf(ear[te][1], wa.y, d);
                d = fmaf(ear[te][2], wb.x, d);
                d = fmaf(ear[te][3], wb.y, d);
                d = fmaf(ear[te][4], wc.x, d);
                d = fmaf(ear[te][5], wc.y, d);
                acc[te] = fmaf(xsS[te * 256 + i], fmaxf(d, 0.f), acc[te]);
            }
        }
        if (ic > 0) {
#pragma unroll
            for (int te = 0; te < TE3; te++)
                partS[(ic - 1) * 320 + te * 64 + o3] = acc[te];
        }
        __syncthreads();
        if (ic == 0) {
#pragma unroll
            for (int te = 0; te < TE3; te++) {
                float s = acc[te];
#pragma unroll
                for (int p = 0; p < 7; p++) s += partS[p * 320 + te * 64 + o3];
                ws[OFF_MP3 + (size_t)(e0 + te) * 64 + o3] = s;
            }
        }
    }
    gbar(bar, NBLK * 4u);

    // ---------------- P3b: gather + lin3 matvec -> x3 ----------------------
    if (bid < NN) {
        const int n = bid;
        const int deg = (int)ws[OFF_CNT + n];
        const int* el = elist_all + n * NE;
        float* x2S = smem;          // 256
        float* pL = smem + 256;     // 7*64
        float* pG = smem + 768;     // 7*64
        if (tid < 256) x2S[tid] = ws[OFF_X2 + n * 256 + tid];
        __syncthreads();
        const int o3 = tid & 63, ic = tid >> 6;
        const float4* l4 = (const float4*)(lin3 + (size_t)o3 * 256 + ic * 32);
        float slin = 0.f;
#pragma unroll
        for (int k = 0; k < 8; k++) {
            const float4 wv = l4[k];
            const int i = ic * 32 + k * 4;
            slin = fmaf(wv.x, x2S[i], slin);
            slin = fmaf(wv.y, x2S[i+1], slin);
            slin = fmaf(wv.z, x2S[i+2], slin);
            slin = fmaf(wv.w, x2S[i+3], slin);
        }
        float sagg = 0.f;
        for (int k = ic; k < deg; k += 8)
            sagg += ws[OFF_MP3 + (size_t)el[k] * 64 + o3];
        if (ic > 0) { pL[(ic-1) * 64 + o3] = slin; pG[(ic-1) * 64 + o3] = sagg; }
        __syncthreads();
        if (ic == 0) {
            float sl = slin, sg = sagg;
#pragma unroll
            for (int p = 0; p < 7; p++) { sl += pL[p*64+o3]; sg += pG[p*64+o3]; }
            const float c = fmaxf((float)deg, 1.f);
            ws[OFF_X3 + n * 64 + o3] = fmaxf(sg / c + sl + b3[o3], 0.f);
        }
    }
    gbar(bar, NBLK * 5u);

    // ---------------- P4: pairwise-L1 CBT ----------------------------------
    if (bid < NN) {
        const int i = bid;
        float* sx = smem;           // 35*64
        for (int idx = tid; idx < NN * 64; idx += 512) sx[idx] = ws[OFF_X3 + idx];
        __syncthreads();
        const int f = tid & 63, jg = tid >> 6;
        const float xi = sx[i * 64 + f];
        for (int j = jg; j < NN; j += 8) {
            float d = fabsf(xi - sx[j * 64 + f]);
#pragma unroll
            for (int off = 32; off > 0; off >>= 1) d += __shfl_xor(d, off);
            if (f == 0) out[i * NN + j] = d;
        }
    }
}

extern "C" void kernel_launch(void* const* d_in, const int* in_sizes, int n_in,
                              void* d_out, int out_size, void* d_ws, size_t ws_size,
                              hipStream_t stream) {
    (void)in_sizes; (void)n_in; (void)out_size; (void)ws_size;
    const float* x    = (const float*)d_in[0];
    const float* ea   = (const float*)d_in[1];
    const int*   ei   = (const int*)d_in[2];
    const float* nn1w = (const float*)d_in[3];
    const float* nn1b = (const float*)d_in[4];
    const float* lin1 = (const float*)d_in[5];
    const float* b1   = (const float*)d_in[6];
    const float* nn2w = (const float*)d_in[7];
    const float* nn2b = (const float*)d_in[8];
    const float* lin2 = (const float*)d_in[9];
    const float* b2   = (const float*)d_in[10];
    const float* nn3w = (const float*)d_in[11];
    const float* nn3b = (const float*)d_in[12];
    const float* lin3 = (const float*)d_in[13];
    const float* b3   = (const float*)d_in[14];

    float* ws = (float*)d_ws;
    init_k<<<1, 64, 0, stream>>>((unsigned*)d_ws);
    mega_k<<<NBLK, 512, 0, stream>>>(ws, x, ea, ei, nn1w, nn1b, lin1, b1,
                                     nn2w, nn2b, lin2, b2, nn3w, nn3b,
                                     lin3, b3, (float*)d_out);
}

// Round 2
// 166.974 us; speedup vs baseline: 1.5122x; 1.5122x over previous
//
#include <hip/hip_runtime.h>

// MGN_NET: 3x NNConv(mean) + ReLU, then pairwise-L1 CBT [35x35]. All fp32.
// 2 dispatches: init (zero barrier counter) + mega-kernel (238 blocks x 512)
// with 5 FENCE-FREE software grid barriers.
// Coherence scheme: all cross-block intermediate data (x1/x2/x3/agg2/agg3)
// is accessed ONLY via agent-scope relaxed atomics (sc1 -> LLC, bypassing the
// non-coherent per-XCD L2), and aggregation uses device atomicAdd (LLC).
// Therefore the barrier needs no buffer_wbl2/buffer_inv (the round-1 killer):
// __syncthreads() drains vmcnt for every wave (sc1 stores complete at LLC),
// then one relaxed atomicAdd + relaxed spin per block.
// Phases:
//   P1  (140 blk = 35n x 4og): edge scan + x1 slice; blocks 140+ zero aggs
//   P2a (238 blk = 119eg x 2ig): layer-2 edge msgs -> atomicAdd agg2
//   P2b (140 blk): lin2 matvec + agg2/c -> x2
//   P3a (238 blk = 238eg x 5e): layer-3 edge msgs -> atomicAdd agg3
//   P3b (35 blk): lin3 matvec + agg3/c -> x3
//   P4  (35 blk): pairwise-L1 CBT -> out
// 238 blocks <= 256 CUs => whole grid co-resident => barrier is deadlock-free.

#define NN 35
#define NE 1190
#define NBLK 238
#define TE2 10
#define TE3 5
#define MAXE 96

// float offsets into ws (bar occupies [0,16) as u32)
#define OFF_X1   64      // 35*256 -> ends 9024
#define OFF_X2   9024    // 35*256 -> ends 17984
#define OFF_X3   17984   // 35*64  -> ends 20224
#define OFF_AGG2 20224   // 35*256 -> ends 29184
#define OFF_AGG3 29184   // 35*64  -> ends 31424

__global__ __launch_bounds__(64) void init_k(unsigned* bar) {
    if (threadIdx.x < 16) bar[threadIdx.x] = 0u;
}

// Coherent (LLC) scalar load/store: sc1 path, bypasses non-coherent XCD L2.
__device__ __forceinline__ float ld_c(const float* p) {
    return __hip_atomic_load(p, __ATOMIC_RELAXED, __HIP_MEMORY_SCOPE_AGENT);
}
__device__ __forceinline__ void st_c(float* p, float v) {
    __hip_atomic_store(p, v, __ATOMIC_RELAXED, __HIP_MEMORY_SCOPE_AGENT);
}

// Fence-free grid barrier. Correctness: __syncthreads() emits
// s_waitcnt vmcnt(0) for every wave => all sc1 stores are at the LLC before
// thread 0 increments the counter (also an LLC op). Readers use sc1 loads,
// which cannot hit stale L2. No wbl2/inv needed.
__device__ __forceinline__ void gbar(unsigned* bar, unsigned target) {
    __syncthreads();
    if (threadIdx.x == 0) {
        __hip_atomic_fetch_add(bar, 1u, __ATOMIC_RELAXED,
                               __HIP_MEMORY_SCOPE_AGENT);
        while (__hip_atomic_load(bar, __ATOMIC_RELAXED,
                                 __HIP_MEMORY_SCOPE_AGENT) < target)
            __builtin_amdgcn_s_sleep(2);
    }
    __syncthreads();
}

__global__ __launch_bounds__(512) void mega_k(
    float* __restrict__ ws, const float* __restrict__ x,
    const float* __restrict__ ea, const int* __restrict__ ei,
    const float* __restrict__ w1, const float* __restrict__ b1w,
    const float* __restrict__ lin1, const float* __restrict__ b1,
    const float* __restrict__ w2, const float* __restrict__ b2w,
    const float* __restrict__ lin2, const float* __restrict__ b2,
    const float* __restrict__ w3, const float* __restrict__ b3w,
    const float* __restrict__ lin3, const float* __restrict__ b3,
    float* __restrict__ out) {
    __shared__ float smem[4096];  // 16 KiB, reused per phase
    unsigned* bar = (unsigned*)ws;
    const int tid = threadIdx.x;
    const int bid = blockIdx.x;

    // ---------------- P1: x1 slices (140 blk) + agg zeroing (98 blk) -------
    if (bid < 140) {
        const int n = bid >> 2, och = bid & 3;
        int* elistS = (int*)smem;          // MAXE
        int* ecntS = (int*)smem + MAXE;    // 1
        float* partS = smem + 128;         // 8*64
        if (tid == 0) *ecntS = 0;
        __syncthreads();
        for (int e = tid; e < NE; e += 512) {
            if (ei[NE + e] == n) {
                const int p = atomicAdd(ecntS, 1);
                if (p < MAXE) elistS[p] = e;
            }
        }
        __syncthreads();
        const int deg = *ecntS;
        const int dl = deg < MAXE ? deg : MAXE;
        const int ol = tid & 63, ech = tid >> 6;
        const int o = och * 64 + ol;
        const float* wr = w1 + o * 6;
        const float wv0 = wr[0], wv1 = wr[1], wv2 = wr[2];
        const float wv3 = wr[3], wv4 = wr[4], wv5 = wr[5];
        const float bb = b1w[o];
        float a = 0.f;
        for (int k = ech; k < dl; k += 8) {
            const int e = elistS[k];
            const float* eap = ea + e * 6;
            float d = bb;
            d = fmaf(eap[0], wv0, d); d = fmaf(eap[1], wv1, d);
            d = fmaf(eap[2], wv2, d); d = fmaf(eap[3], wv3, d);
            d = fmaf(eap[4], wv4, d); d = fmaf(eap[5], wv5, d);
            a = fmaf(x[ei[e]], fmaxf(d, 0.f), a);
        }
        partS[ech * 64 + ol] = a;
        __syncthreads();
        if (ech == 0) {
            float s = a;
#pragma unroll
            for (int p = 1; p < 8; p++) s += partS[p * 64 + ol];
            const float c = fmaxf((float)deg, 1.f);
            st_c(ws + OFF_X1 + n * 256 + o,
                 fmaxf(s / c + x[n] * lin1[o] + b1[o], 0.f));
        }
    } else {
        // zero agg2 (8960) + agg3 (2240), contiguous at OFF_AGG2
        const int idx = (bid - 140) * 512 + tid;
        if (idx < 8960 + 2240) st_c(ws + OFF_AGG2 + idx, 0.f);
    }
    gbar(bar, NBLK * 1u);

    // ---------------- P2a: layer-2 edge messages -> agg2 -------------------
    {
        const int eg = bid >> 1, ig = bid & 1;
        const int e0 = eg * TE2;
        int* srcsS = (int*)smem;         // 10
        int* dstsS = (int*)smem + 16;    // 10
        float* easS = smem + 32;         // 60
        float* xsS = smem + 96;          // 10*128 -> ends 1376
        float* partS = smem + 1408;      // 10*256 -> ends 3968
        if (tid < TE2) { srcsS[tid] = ei[e0 + tid]; dstsS[tid] = ei[NE + e0 + tid]; }
        if (tid >= 64 && tid < 64 + TE2 * 6) {
            const int t = tid - 64;
            easS[t] = ea[e0 * 6 + t];
        }
        __syncthreads();
        for (int idx = tid; idx < TE2 * 128; idx += 512) {
            const int te = idx >> 7, il = idx & 127;
            xsS[te * 128 + il] = ld_c(ws + OFF_X1 + srcsS[te] * 256 + ig * 128 + il);
        }
        __syncthreads();
        const int o = tid & 255, ich = tid >> 8;
        float ear[TE2][6];
#pragma unroll
        for (int te = 0; te < TE2; te++)
#pragma unroll
            for (int v = 0; v < 6; v++) ear[te][v] = easS[te * 6 + v];
        float acc[TE2] = {};
        for (int ii = 0; ii < 64; ii++) {
            const int il = ich * 64 + ii;
            const int i = ig * 128 + il;
            const float* wp = w2 + (size_t)(i * 256 + o) * 6;
            const float2 wa = *(const float2*)wp;
            const float2 wb = *(const float2*)(wp + 2);
            const float2 wc = *(const float2*)(wp + 4);
            const float b = b2w[i * 256 + o];
#pragma unroll
            for (int te = 0; te < TE2; te += 2) {
                float dx = b, dy = b;
                dx = fmaf(ear[te][0], wa.x, dx); dy = fmaf(ear[te+1][0], wa.x, dy);
                dx = fmaf(ear[te][1], wa.y, dx); dy = fmaf(ear[te+1][1], wa.y, dy);
                dx = fmaf(ear[te][2], wb.x, dx); dy = fmaf(ear[te+1][2], wb.x, dy);
                dx = fmaf(ear[te][3], wb.y, dx); dy = fmaf(ear[te+1][3], wb.y, dy);
                dx = fmaf(ear[te][4], wc.x, dx); dy = fmaf(ear[te+1][4], wc.x, dy);
                dx = fmaf(ear[te][5], wc.y, dx); dy = fmaf(ear[te+1][5], wc.y, dy);
                dx = fmaxf(dx, 0.f);             dy = fmaxf(dy, 0.f);
                acc[te]   = fmaf(xsS[te * 128 + il], dx, acc[te]);
                acc[te+1] = fmaf(xsS[(te+1) * 128 + il], dy, acc[te+1]);
            }
        }
        if (ich == 1) {
#pragma unroll
            for (int te = 0; te < TE2; te++) partS[te * 256 + o] = acc[te];
        }
        __syncthreads();
        if (ich == 0) {
#pragma unroll
            for (int te = 0; te < TE2; te++)
                atomicAdd(ws + OFF_AGG2 + dstsS[te] * 256 + o,
                          acc[te] + partS[te * 256 + o]);
        }
    }
    gbar(bar, NBLK * 2u);

    // ---------------- P2b: x2 = relu(agg2/c + lin2.x1 + b2) ----------------
    if (bid < 140) {
        const int n = bid >> 2, og = bid & 3;
        int* cntS = (int*)smem;          // 1
        float* xrowS = smem + 64;        // 256
        float* partS = smem + 320;       // 8*64
        if (tid == 0) *cntS = 0;
        __syncthreads();
        int lc = 0;
        for (int e = tid; e < NE; e += 512) lc += (ei[NE + e] == n) ? 1 : 0;
        if (lc) atomicAdd(cntS, lc);
        if (tid < 256) xrowS[tid] = ld_c(ws + OFF_X1 + n * 256 + tid);
        __syncthreads();
        const int deg = *cntS;
        const int ol = tid & 63, ic = tid >> 6;
        const int o = og * 64 + ol;
        const float4* l4 = (const float4*)(lin2 + (size_t)o * 256 + ic * 32);
        float slin = 0.f;
#pragma unroll
        for (int k = 0; k < 8; k++) {
            const float4 wv = l4[k];
            const int i = ic * 32 + k * 4;
            slin = fmaf(wv.x, xrowS[i], slin);
            slin = fmaf(wv.y, xrowS[i + 1], slin);
            slin = fmaf(wv.z, xrowS[i + 2], slin);
            slin = fmaf(wv.w, xrowS[i + 3], slin);
        }
        partS[ic * 64 + ol] = slin;
        __syncthreads();
        if (ic == 0) {
            float s = slin;
#pragma unroll
            for (int p = 1; p < 8; p++) s += partS[p * 64 + ol];
            const float c = fmaxf((float)deg, 1.f);
            const float v = ld_c(ws + OFF_AGG2 + n * 256 + o) / c + s + b2[o];
            st_c(ws + OFF_X2 + n * 256 + o, fmaxf(v, 0.f));
        }
    }
    gbar(bar, NBLK * 3u);

    // ---------------- P3a: layer-3 edge messages -> agg3 -------------------
    {
        const int e0 = bid * TE3;
        int* srcsS = (int*)smem;         // 5
        int* dstsS = (int*)smem + 8;     // 5
        float* easS = smem + 16;         // 30
        float* xsS = smem + 64;          // 5*256 -> ends 1344
        float* partS = smem + 1344;      // 7*5*64 -> ends 3584
        if (tid < TE3) { srcsS[tid] = ei[e0 + tid]; dstsS[tid] = ei[NE + e0 + tid]; }
        if (tid >= 64 && tid < 64 + TE3 * 6) {
            const int t = tid - 64;
            easS[t] = ea[e0 * 6 + t];
        }
        __syncthreads();
        for (int idx = tid; idx < TE3 * 256; idx += 512) {
            const int te = idx >> 8, il = idx & 255;
            xsS[te * 256 + il] = ld_c(ws + OFF_X2 + srcsS[te] * 256 + il);
        }
        __syncthreads();
        const int o3 = tid & 63, ic = tid >> 6;
        float ear[TE3][6];
#pragma unroll
        for (int te = 0; te < TE3; te++)
#pragma unroll
            for (int v = 0; v < 6; v++) ear[te][v] = easS[te * 6 + v];
        float acc[TE3] = {};
        for (int ii = 0; ii < 32; ii++) {
            const int i = ic * 32 + ii;
            const float* wp = w3 + (size_t)(i * 64 + o3) * 6;
            const float2 wa = *(const float2*)wp;
            const float2 wb = *(const float2*)(wp + 2);
            const float2 wc = *(const float2*)(wp + 4);
            const float b = b3w[i * 64 + o3];
#pragma unroll
            for (int te = 0; te < TE3; te++) {
                float d = b;
                d = fmaf(ear[te][0], wa.x, d);
                d = fmaf(ear[te][1], wa.y, d);
                d = fmaf(ear[te][2], wb.x, d);
                d = fmaf(ear[te][3], wb.y, d);
                d = fmaf(ear[te][4], wc.x, d);
                d = fmaf(ear[te][5], wc.y, d);
                acc[te] = fmaf(xsS[te * 256 + i], fmaxf(d, 0.f), acc[te]);
            }
        }
        if (ic > 0) {
#pragma unroll
            for (int te = 0; te < TE3; te++)
                partS[(ic - 1) * 320 + te * 64 + o3] = acc[te];
        }
        __syncthreads();
        if (ic == 0) {
#pragma unroll
            for (int te = 0; te < TE3; te++) {
                float s = acc[te];
#pragma unroll
                for (int p = 0; p < 7; p++) s += partS[p * 320 + te * 64 + o3];
                atomicAdd(ws + OFF_AGG3 + dstsS[te] * 64 + o3, s);
            }
        }
    }
    gbar(bar, NBLK * 4u);

    // ---------------- P3b: x3 = relu(agg3/c + lin3.x2 + b3) ----------------
    if (bid < NN) {
        const int n = bid;
        int* cntS = (int*)smem;          // 1
        float* x2S = smem + 64;          // 256
        float* partS = smem + 320;       // 8*64
        if (tid == 0) *cntS = 0;
        __syncthreads();
        int lc = 0;
        for (int e = tid; e < NE; e += 512) lc += (ei[NE + e] == n) ? 1 : 0;
        if (lc) atomicAdd(cntS, lc);
        if (tid < 256) x2S[tid] = ld_c(ws + OFF_X2 + n * 256 + tid);
        __syncthreads();
        const int deg = *cntS;
        const int o3 = tid & 63, ic = tid >> 6;
        const float4* l4 = (const float4*)(lin3 + (size_t)o3 * 256 + ic * 32);
        float slin = 0.f;
#pragma unroll
        for (int k = 0; k < 8; k++) {
            const float4 wv = l4[k];
            const int i = ic * 32 + k * 4;
            slin = fmaf(wv.x, x2S[i], slin);
            slin = fmaf(wv.y, x2S[i + 1], slin);
            slin = fmaf(wv.z, x2S[i + 2], slin);
            slin = fmaf(wv.w, x2S[i + 3], slin);
        }
        partS[ic * 64 + o3] = slin;
        __syncthreads();
        if (ic == 0) {
            float s = slin;
#pragma unroll
            for (int p = 1; p < 8; p++) s += partS[p * 64 + o3];
            const float c = fmaxf((float)deg, 1.f);
            const float v = ld_c(ws + OFF_AGG3 + n * 64 + o3) / c + s + b3[o3];
            st_c(ws + OFF_X3 + n * 64 + o3, fmaxf(v, 0.f));
        }
    }
    gbar(bar, NBLK * 5u);

    // ---------------- P4: pairwise-L1 CBT ----------------------------------
    if (bid < NN) {
        float* sx = smem;  // 35*64
        for (int idx = tid; idx < NN * 64; idx += 512)
            sx[idx] = ld_c(ws + OFF_X3 + idx);
        __syncthreads();
        const int f = tid & 63, jg = tid >> 6;
        const float xi = sx[bid * 64 + f];
        for (int j = jg; j < NN; j += 8) {
            float d = fabsf(xi - sx[j * 64 + f]);
#pragma unroll
            for (int off = 32; off > 0; off >>= 1) d += __shfl_xor(d, off);
            if (f == 0) out[bid * NN + j] = d;
        }
    }
}

extern "C" void kernel_launch(void* const* d_in, const int* in_sizes, int n_in,
                              void* d_out, int out_size, void* d_ws, size_t ws_size,
                              hipStream_t stream) {
    (void)in_sizes; (void)n_in; (void)out_size; (void)ws_size;
    const float* x    = (const float*)d_in[0];
    const float* ea   = (const float*)d_in[1];
    const int*   ei   = (const int*)d_in[2];
    const float* nn1w = (const float*)d_in[3];
    const float* nn1b = (const float*)d_in[4];
    const float* lin1 = (const float*)d_in[5];
    const float* b1   = (const float*)d_in[6];
    const float* nn2w = (const float*)d_in[7];
    const float* nn2b = (const float*)d_in[8];
    const float* lin2 = (const float*)d_in[9];
    const float* b2   = (const float*)d_in[10];
    const float* nn3w = (const float*)d_in[11];
    const float* nn3b = (const float*)d_in[12];
    const float* lin3 = (const float*)d_in[13];
    const float* b3   = (const float*)d_in[14];

    float* ws = (float*)d_ws;
    init_k<<<1, 64, 0, stream>>>((unsigned*)d_ws);
    mega_k<<<NBLK, 512, 0, stream>>>(ws, x, ea, ei, nn1w, nn1b, lin1, b1,
                                     nn2w, nn2b, lin2, b2, nn3w, nn3b,
                                     lin3, b3, (float*)d_out);
}